// Round 1
// baseline (1875.642 us; speedup 1.0000x reference)
//
#include <hip/hip_runtime.h>
#include <math.h>

#define NB   256
#define LSEQ 1800
#define NF   50
#define NE   4
#define NH   32
#define G3   96
#define ND   64
#define NHU  32
#define CHUNK 24
#define TBLK  8
#define NCHUNK (LSEQ / CHUNK)   // 75
#define NBLK   (CHUNK / TBLK)   // 3
#define WPB    8                // routed units (waves) per block

typedef float v2f __attribute__((ext_vector_type(2)));

__device__ __forceinline__ v2f v2fma(v2f a, v2f b, v2f c) {
    return __builtin_elementwise_fma(a, b, c);
}
__device__ __forceinline__ v2f mkv2(float a, float b) { v2f t; t.x = a; t.y = b; return t; }
__device__ __forceinline__ v2f splat2(float s) { v2f t; t.x = s; t.y = s; return t; }

// ---------------------------------------------------------------------------
// Kernel 1: fold input projection into layer-0 input weights.
// Cg[e][f][g] = sum_d Wih0[e][g][d] * W_in[d][f]
// ---------------------------------------------------------------------------
__global__ void compute_C_kernel(const float* __restrict__ Wih0,
                                 const float* __restrict__ W_in,
                                 float* __restrict__ Cg) {
    int e = blockIdx.x;
    for (int idx = threadIdx.x; idx < NF * G3; idx += blockDim.x) {
        int f = idx / G3;
        int g = idx - f * G3;
        const float* wr = Wih0 + ((size_t)e * G3 + g) * ND;
        float s = 0.f;
        #pragma unroll 8
        for (int d = 0; d < ND; d++) s += wr[d] * W_in[d * NF + f];
        Cg[(size_t)e * NF * G3 + idx] = s;
    }
}

// Fast transcendentals on v_exp_f32 / v_rcp_f32.
__device__ __forceinline__ float fsig(float x) {
    float e = __builtin_amdgcn_exp2f(-1.442695041f * x);
    return __builtin_amdgcn_rcpf(1.f + e);
}
__device__ __forceinline__ float ftanh(float x) {
    x = fmaxf(x, -20.f);
    float e = __builtin_amdgcn_exp2f(-2.885390082f * x);
    return (1.f - e) * __builtin_amdgcn_rcpf(1.f + e);
}

// ---------------------------------------------------------------------------
// One 512-thread block = 8 waves = 8 routed (batch, expert=blockIdx.x) units.
// Compaction: every block redundantly computes the gating table for all 256
// batches, builds expert-e's routed-batch list in LDS, and wave w takes slot
// blockIdx.y*8+w.  This guarantees 2 ACTIVE waves per SIMD (TLP to hide the
// serial GRU chain's stall cycles) and shares the 19.2 KB CT tile across 8
// units.  Inner per-step math identical to the single-wave version.
// ---------------------------------------------------------------------------
__global__ __launch_bounds__(512, 2)
void moe_gru_kernel(const float* __restrict__ x,
                    const int*   __restrict__ horizon,
                    const float* __restrict__ emb,
                    const float* __restrict__ W_gate,
                    const float* __restrict__ b_gate,
                    const float* __restrict__ b_in,
                    const float* __restrict__ Wih0,
                    const float* __restrict__ Whh0,
                    const float* __restrict__ bih0,
                    const float* __restrict__ bhh0,
                    const float* __restrict__ Wih1,
                    const float* __restrict__ Whh1,
                    const float* __restrict__ bih1,
                    const float* __restrict__ bhh1,
                    const float* __restrict__ Wh1,
                    const float* __restrict__ bh1,
                    const float* __restrict__ Wh2,
                    const float* __restrict__ bh2,
                    const float* __restrict__ Cg,
                    float* __restrict__ out) {
    // CT[4800] | xs[8][1200] | bb[8][64] | h1[8][32] | wE[256] | lst[256] | cnt
    __shared__ __align__(16) float smem[15688];
    float* CT  = smem;                          // shared folded xg0 weights
    float* wE  = smem + 15168;                  // weight of expert e per batch
    int*   lst = (int*)(smem + 15424);          // compacted batch list
    int*   pcnt = (int*)(smem + 15680);

    const int e    = blockIdx.x;
    const int t512 = threadIdx.x;
    const int wave = t512 >> 6;
    const int tid  = t512 & 63;
    const int j    = tid & 31;
    const int hlf  = tid >> 5;
    const int k0h  = hlf << 4;

    float* xs  = smem + 4800  + wave * (CHUNK * NF);   // per-wave x chunk
    float* bbL = smem + 14400 + wave * 64;             // per-wave b_in+h_embed
    float* h1L = smem + 14912 + wave * 32;             // per-wave h1 exchange

    // ---- phase 0: cooperative CT staging + per-batch gating flags ----
    for (int idx = t512; idx < NF * G3; idx += 512)
        CT[idx] = Cg[(size_t)e * NF * G3 + idx];
    if (t512 < NB) {
        int hor = horizon[t512];
        const float* he = emb + (size_t)hor * ND;
        float lg[NE];
        #pragma unroll
        for (int q = 0; q < NE; q++) {
            float s = b_gate[q];
            for (int d = 0; d < ND; d++) s += he[d] * W_gate[q * ND + d];
            lg[q] = s;
        }
        int i1 = 0;
        #pragma unroll
        for (int q = 1; q < NE; q++) if (lg[q] > lg[i1]) i1 = q;
        int i2 = (i1 == 0) ? 1 : 0;
        #pragma unroll
        for (int q = 0; q < NE; q++) if (q != i1 && lg[q] > lg[i2]) i2 = q;
        float ex2 = expf(lg[i2] - lg[i1]);
        float w1 = 1.f / (1.f + ex2);
        float w2 = ex2 / (1.f + ex2);
        wE[t512] = (e == i1) ? w1 : (e == i2) ? w2 : 0.f;
    }
    __syncthreads();
    // ---- phase 1: serial compaction (one-time, ~256 iters) ----
    if (t512 == 0) {
        int c = 0;
        for (int t = 0; t < NB; t++) if (wE[t] > 0.f) lst[c++] = t;
        *pcnt = c;
    }
    __syncthreads();

    const int slot = blockIdx.y * WPB + wave;
    const int cnt  = *pcnt;
    if (slot >= cnt) return;                   // wave-uniform, after barriers
    const int   b   = lst[slot];
    const float wgt = wE[b];

    // ---- stage b_in + h_embed (wave-synchronous) ----
    {
        int hor = horizon[b];
        bbL[tid] = emb[(size_t)hor * ND + tid] + b_in[tid];
    }

    // ---- per-lane weights ----
    // selA: half0 -> Whh0 rows {j, j+32, j+64}; half1 -> Wih1 rows (full 32-k)
    v2f sA0[16], sA1[16], sA2[16];
    // wB: Whh1 rows {j, j+32, j+64}, k-half [k0h, k0h+16)
    v2f wB0[8], wB1[8], wB2[8];
    {
        const float* baseA = (hlf ? Wih1 : Whh0) + (size_t)e * G3 * NH;
        const float* rA0 = baseA + (size_t)j * NH;
        const float* rA1 = baseA + (size_t)(j + 32) * NH;
        const float* rA2 = baseA + (size_t)(j + 64) * NH;
        #pragma unroll
        for (int q4 = 0; q4 < 8; q4++) {
            float4 qa = ((const float4*)rA0)[q4];
            sA0[2*q4] = mkv2(qa.x, qa.y); sA0[2*q4+1] = mkv2(qa.z, qa.w);
            float4 qb = ((const float4*)rA1)[q4];
            sA1[2*q4] = mkv2(qb.x, qb.y); sA1[2*q4+1] = mkv2(qb.z, qb.w);
            float4 qc = ((const float4*)rA2)[q4];
            sA2[2*q4] = mkv2(qc.x, qc.y); sA2[2*q4+1] = mkv2(qc.z, qc.w);
        }
        const float* baseB = Whh1 + (size_t)e * G3 * NH;
        const float* rB0 = baseB + (size_t)j * NH + k0h;
        const float* rB1 = baseB + (size_t)(j + 32) * NH + k0h;
        const float* rB2 = baseB + (size_t)(j + 64) * NH + k0h;
        #pragma unroll
        for (int q4 = 0; q4 < 4; q4++) {
            float4 qa = ((const float4*)rB0)[q4];
            wB0[2*q4] = mkv2(qa.x, qa.y); wB0[2*q4+1] = mkv2(qa.z, qa.w);
            float4 qb = ((const float4*)rB1)[q4];
            wB1[2*q4] = mkv2(qb.x, qb.y); wB1[2*q4+1] = mkv2(qb.z, qb.w);
            float4 qc = ((const float4*)rB2)[q4];
            wB2[2*q4] = mkv2(qc.x, qc.y); wB2[2*q4+1] = mkv2(qc.z, qc.w);
        }
    }
    const float selb0 = hlf ? bih1[e*G3 + j]      : bhh0[e*G3 + j];
    const float selb1 = hlf ? bih1[e*G3 + j + 32] : bhh0[e*G3 + j + 32];
    const float selb2 = hlf ? bih1[e*G3 + j + 64] : bhh0[e*G3 + j + 64];
    const float whb0  = hlf ? 0.f : bhh1[e*G3 + j];
    const float whb1  = hlf ? 0.f : bhh1[e*G3 + j + 32];
    const float whb2  = hlf ? 0.f : bhh1[e*G3 + j + 64];

    // dreg = bih0 + Wih0 @ (b_in + h_embed), added once (half0 side of reduce)
    float dreg0, dreg1, dreg2;
    {
        float s0 = bih0[e*G3 + j], s1 = bih0[e*G3 + j + 32], s2 = bih0[e*G3 + j + 64];
        const float* w0 = Wih0 + ((size_t)e * G3 + j) * ND;
        const float* w1 = Wih0 + ((size_t)e * G3 + j + 32) * ND;
        const float* w2 = Wih0 + ((size_t)e * G3 + j + 64) * ND;
        for (int d = 0; d < ND; d++) {
            float bb = bbL[d];
            s0 += w0[d] * bb; s1 += w1[d] * bb; s2 += w2[d] * bb;
        }
        dreg0 = hlf ? 0.f : s0;
        dreg1 = hlf ? 0.f : s1;
        dreg2 = hlf ? 0.f : s2;
    }

    // ---- pipeline state ----
    v2f h0v[16], h1v[8];
    #pragma unroll
    for (int k = 0; k < 16; k++) h0v[k] = splat2(0.f);
    #pragma unroll
    for (int k = 0; k < 8; k++)  h1v[k] = splat2(0.f);
    float hold = 0.f;                    // half0: h0_j ; half1: h1_j (skewed)
    float lmul = hlf ? 0.f : 1.f;        // neutralizes the fake first L1 step
    if (tid < 32) h1L[tid] = 0.f;

    const float* xg = x + (size_t)b * LSEQ * NF;

    for (int ch = 0; ch < NCHUNK; ch++) {
        // stage x chunk (contiguous float4 global loads), transpose to [f][t]
        {
            const float4* xc4 = (const float4*)(xg + (size_t)ch * CHUNK * NF);
            for (int i4 = tid; i4 < (CHUNK * NF) / 4; i4 += 64) {
                float4 v = xc4[i4];
                int idx = i4 * 4;
                #pragma unroll
                for (int u = 0; u < 4; u++) {
                    int id = idx + u;
                    int it = (int)(((unsigned)id * 5243u) >> 18);   // id/50
                    int f  = id - it * 50;
                    float val = (u == 0) ? v.x : (u == 1) ? v.y : (u == 2) ? v.z : v.w;
                    xs[f * CHUNK + it] = val;
                }
            }
        }

        for (int blk = 0; blk < NBLK; blk++) {
            const int ib0 = blk * TBLK;
            // ---- xg0 partials for TBLK steps (f-split across halves) ----
            v2f a0[4], a1[4], a2[4];
            #pragma unroll
            for (int p = 0; p < 4; p++) {
                a0[p] = splat2(dreg0); a1[p] = splat2(dreg1); a2[p] = splat2(dreg2);
            }
            {
                const int fb = 25 * hlf;
                #pragma unroll 5
                for (int f = 0; f < 25; f++) {
                    const int fg = fb + f;
                    float c0 = CT[fg * G3 + j];
                    float c1 = CT[fg * G3 + j + 32];
                    float c2 = CT[fg * G3 + j + 64];
                    const float4* xp = (const float4*)(xs + fg * CHUNK + ib0);
                    float4 xa = xp[0], xb = xp[1];
                    v2f xv[4] = { mkv2(xa.x, xa.y), mkv2(xa.z, xa.w),
                                  mkv2(xb.x, xb.y), mkv2(xb.z, xb.w) };
                    v2f w0 = splat2(c0), w1 = splat2(c1), w2 = splat2(c2);
                    #pragma unroll
                    for (int p = 0; p < 4; p++) {
                        a0[p] = v2fma(w0, xv[p], a0[p]);
                        a1[p] = v2fma(w1, xv[p], a1[p]);
                        a2[p] = v2fma(w2, xv[p], a2[p]);
                    }
                }
            }
            // cross-half reduce of xg0 (off the per-step chain)
            #pragma unroll
            for (int p = 0; p < 4; p++) {
                a0[p].x += __shfl_xor(a0[p].x, 32, 64); a0[p].y += __shfl_xor(a0[p].y, 32, 64);
                a1[p].x += __shfl_xor(a1[p].x, 32, 64); a1[p].y += __shfl_xor(a1[p].y, 32, 64);
                a2[p].x += __shfl_xor(a2[p].x, 32, 64); a2[p].y += __shfl_xor(a2[p].y, 32, 64);
            }

            // ---- TBLK pipelined steps: L0(t) on half0 || L1(t-1) on half1 ----
            #pragma unroll
            for (int i = 0; i < TBLK; i++) {
                // B-dots (k-half over h1 from LDS), start the xor32 reduce
                v2f dB0 = mkv2(whb0, 0.f), dB1 = mkv2(whb1, 0.f), dB2 = mkv2(whb2, 0.f);
                #pragma unroll
                for (int k = 0; k < 8; k++) {
                    dB0 = v2fma(wB0[k], h1v[k], dB0);
                    dB1 = v2fma(wB1[k], h1v[k], dB1);
                    dB2 = v2fma(wB2[k], h1v[k], dB2);
                }
                float B0 = dB0.x + dB0.y, B1 = dB1.x + dB1.y, B2 = dB2.x + dB2.y;
                float R0 = B0 + __shfl_xor(B0, 32, 64);   // covered by A-dots
                float R1 = B1 + __shfl_xor(B1, 32, 64);
                float R2 = B2 + __shfl_xor(B2, 32, 64);
                // A-dots: full dots over transported h0
                v2f dA0 = mkv2(selb0, 0.f), dA1 = mkv2(selb1, 0.f), dA2 = mkv2(selb2, 0.f);
                #pragma unroll
                for (int k = 0; k < 16; k++) {
                    dA0 = v2fma(sA0[k], h0v[k], dA0);
                    dA1 = v2fma(sA1[k], h0v[k], dA1);
                    dA2 = v2fma(sA2[k], h0v[k], dA2);
                }
                float A0 = dA0.x + dA0.y, A1 = dA1.x + dA1.y, A2 = dA2.x + dA2.y;
                const float ac0 = a0[i >> 1][i & 1];
                const float ac1 = a1[i >> 1][i & 1];
                const float ac2 = a2[i >> 1][i & 1];
                // gate assembly (uniform instructions, per-half operand select)
                float o0   = hlf ? R0 : ac0;
                float o1   = hlf ? R1 : ac1;
                float npre = hlf ? A2 : ac2;
                float gn   = hlf ? R2 : A2;
                float r = fsig(A0 + o0);
                float z = fsig(A1 + o1);
                float n = ftanh(npre + r * gn);
                float hnew = (n + z * (hold - n)) * lmul;
                hold = hnew;
                lmul = 1.f;
                // h1 exchange via LDS (round trip covered by transport + A-dots)
                if (hlf) h1L[j] = hnew;
                const float4* h1q = (const float4*)(h1L + k0h);
                float4 q0 = h1q[0], q1 = h1q[1], q2 = h1q[2], q3 = h1q[3];
                h1v[0] = mkv2(q0.x, q0.y); h1v[1] = mkv2(q0.z, q0.w);
                h1v[2] = mkv2(q1.x, q1.y); h1v[3] = mkv2(q1.z, q1.w);
                h1v[4] = mkv2(q2.x, q2.y); h1v[5] = mkv2(q2.z, q2.w);
                h1v[6] = mkv2(q3.x, q3.y); h1v[7] = mkv2(q3.z, q3.w);
                // h0 broadcast via v_readlane: VALU-only, no DS latency
                {
                    int hni = __float_as_int(hnew);
                    #pragma unroll
                    for (int k = 0; k < 16; k++) {
                        float e0 = __int_as_float(__builtin_amdgcn_readlane(hni, 2*k));
                        float e1 = __int_as_float(__builtin_amdgcn_readlane(hni, 2*k+1));
                        h0v[k] = mkv2(e0, e1);
                    }
                }
            }
        }
    }

    // ---- epilogue: L1(LSEQ-1) (results used from half1 only) ----
    {
        v2f dA0 = mkv2(selb0, 0.f), dA1 = mkv2(selb1, 0.f), dA2 = mkv2(selb2, 0.f);
        #pragma unroll
        for (int k = 0; k < 16; k++) {
            dA0 = v2fma(sA0[k], h0v[k], dA0);
            dA1 = v2fma(sA1[k], h0v[k], dA1);
            dA2 = v2fma(sA2[k], h0v[k], dA2);
        }
        v2f dB0 = mkv2(whb0, 0.f), dB1 = mkv2(whb1, 0.f), dB2 = mkv2(whb2, 0.f);
        #pragma unroll
        for (int k = 0; k < 8; k++) {
            dB0 = v2fma(wB0[k], h1v[k], dB0);
            dB1 = v2fma(wB1[k], h1v[k], dB1);
            dB2 = v2fma(wB2[k], h1v[k], dB2);
        }
        float A0 = dA0.x + dA0.y, A1 = dA1.x + dA1.y, A2 = dA2.x + dA2.y;
        float B0 = dB0.x + dB0.y, B1 = dB1.x + dB1.y, B2 = dB2.x + dB2.y;
        float R0 = B0 + __shfl_xor(B0, 32, 64);
        float R1 = B1 + __shfl_xor(B1, 32, 64);
        float R2 = B2 + __shfl_xor(B2, 32, 64);
        float r = fsig(A0 + R0);
        float z = fsig(A1 + R1);
        float n = ftanh(A2 + r * R2);
        float hfin = n + z * (hold - n);
        if (hlf) h1L[j] = hfin;
    }

    // ---- head MLP + weighted accumulation ----
    if (tid < 32) {
        float s = bh1[e * NHU + tid];
        const float* wr = Wh1 + ((size_t)e * NHU + tid) * NH;
        #pragma unroll
        for (int d = 0; d < NH; d++) s += wr[d] * h1L[d];
        float hid = fmaxf(s, 0.f);
        float c = hid * Wh2[e * NHU + tid];
        #pragma unroll
        for (int off = 16; off > 0; off >>= 1) c += __shfl_down(c, off, 64);
        if (tid == 0) atomicAdd(out + b, wgt * (c + bh2[e]));
    }
}

extern "C" void kernel_launch(void* const* d_in, const int* in_sizes, int n_in,
                              void* d_out, int out_size, void* d_ws, size_t ws_size,
                              hipStream_t stream) {
    const float* x       = (const float*)d_in[0];
    const int*   horizon = (const int*)  d_in[1];
    const float* W_in    = (const float*)d_in[2];
    const float* b_in    = (const float*)d_in[3];
    const float* emb     = (const float*)d_in[4];
    const float* W_gate  = (const float*)d_in[5];
    const float* b_gate  = (const float*)d_in[6];
    const float* Wih0    = (const float*)d_in[7];
    const float* Whh0    = (const float*)d_in[8];
    const float* bih0    = (const float*)d_in[9];
    const float* bhh0    = (const float*)d_in[10];
    const float* Wih1    = (const float*)d_in[11];
    const float* Whh1    = (const float*)d_in[12];
    const float* bih1    = (const float*)d_in[13];
    const float* bhh1    = (const float*)d_in[14];
    const float* Wh1     = (const float*)d_in[15];
    const float* bh1     = (const float*)d_in[16];
    const float* Wh2     = (const float*)d_in[17];
    const float* bh2     = (const float*)d_in[18];
    float* out = (float*)d_out;
    float* Cg  = (float*)d_ws;   // NE*NF*G3 floats = 76.8 KB

    hipMemsetAsync(d_out, 0, NB * sizeof(float), stream);
    compute_C_kernel<<<dim3(NE), dim3(256), 0, stream>>>(Wih0, W_in, Cg);
    moe_gru_kernel<<<dim3(NE, (NB + WPB - 1) / WPB), dim3(512), 0, stream>>>(
        x, horizon, emb, W_gate, b_gate, b_in,
        Wih0, Whh0, bih0, bhh0, Wih1, Whh1, bih1, bhh1,
        Wh1, bh1, Wh2, bh2, Cg, out);
}

// Round 2
// 1458.837 us; speedup vs baseline: 1.2857x; 1.2857x over previous
//
#include <hip/hip_runtime.h>
#include <math.h>

#define NB   256
#define LSEQ 1800
#define NF   50
#define NE   4
#define NH   32
#define G3   96
#define ND   64
#define NHU  32
#define CHUNK 72
#define TBLK  8
#define NCHUNK (LSEQ / CHUNK)   // 25
#define NBLK   (CHUNK / TBLK)   // 9

typedef float v2f __attribute__((ext_vector_type(2)));

__device__ __forceinline__ v2f v2fma(v2f a, v2f b, v2f c) {
    return __builtin_elementwise_fma(a, b, c);
}
__device__ __forceinline__ v2f mkv2(float a, float b) { v2f t; t.x = a; t.y = b; return t; }
__device__ __forceinline__ v2f splat2(float s) { v2f t; t.x = s; t.y = s; return t; }

// xor-32 sum across wave halves via v_permlane32_swap_b32 (gfx950 VALU op).
// After swap(t,u) with t=u=v: t[i<32]=v[i^32], t[i>=32]=v[i];
//                             u[i>=32]=v[i^32], u[i<32]=v[i].
// t+u == v + v[lane^32] in EVERY lane.  Replaces ds_bpermute (~120cy DS
// latency + lgkm wait) with 3 VALU ops (~6cy).
__device__ __forceinline__ float xor32sum(float v) {
    float t = v, u = v;
    asm("v_permlane32_swap_b32 %0, %1" : "+v"(t), "+v"(u));
    return t + u;
}

// ---------------------------------------------------------------------------
// Kernel 1: fold input projection into layer-0 input weights.
// Cg[e][f][g] = sum_d Wih0[e][g][d] * W_in[d][f]   (compact [f][96] layout,
// repacked to [f][j][4] at LDS-staging time inside the main kernel)
// ---------------------------------------------------------------------------
__global__ void compute_C_kernel(const float* __restrict__ Wih0,
                                 const float* __restrict__ W_in,
                                 float* __restrict__ Cg) {
    int e = blockIdx.x;
    for (int idx = threadIdx.x; idx < NF * G3; idx += blockDim.x) {
        int f = idx / G3;
        int g = idx - f * G3;
        const float* wr = Wih0 + ((size_t)e * G3 + g) * ND;
        float s = 0.f;
        #pragma unroll 8
        for (int d = 0; d < ND; d++) s += wr[d] * W_in[d * NF + f];
        Cg[(size_t)e * NF * G3 + idx] = s;
    }
}

// Fast transcendentals on v_exp_f32 / v_rcp_f32.
__device__ __forceinline__ float fsig(float x) {
    float e = __builtin_amdgcn_exp2f(-1.442695041f * x);
    return __builtin_amdgcn_rcpf(1.f + e);
}
__device__ __forceinline__ float ftanh(float x) {
    x = fmaxf(x, -20.f);
    float e = __builtin_amdgcn_exp2f(-2.885390082f * x);
    return (1.f - e) * __builtin_amdgcn_rcpf(1.f + e);
}

// ---------------------------------------------------------------------------
// One 64-thread (single-wave) block per (batch, expert); unrouted blocks exit.
// Role split with 1-step skew: half0 lane j = L0(t) row j; half1 lane j =
// L1(t-1) row j.  All cross-half reductions via v_permlane32_swap (VALU);
// h0 broadcast via v_readlane; h1 exchanged through LDS (round trip covered
// by the readlane transport + A-dots).  No barriers (single wave).
// CT held in LDS as [f][j][4] = rows {j, j+32, j+64, pad}: one ds_read_b128
// per (f, lane) instead of three ds_read_b32 (perfectly banked at 16B/lane).
// ---------------------------------------------------------------------------
__global__ __launch_bounds__(64, 1)
void moe_gru_kernel(const float* __restrict__ x,
                    const int*   __restrict__ horizon,
                    const float* __restrict__ emb,
                    const float* __restrict__ W_gate,
                    const float* __restrict__ b_gate,
                    const float* __restrict__ b_in,
                    const float* __restrict__ Wih0,
                    const float* __restrict__ Whh0,
                    const float* __restrict__ bih0,
                    const float* __restrict__ bhh0,
                    const float* __restrict__ Wih1,
                    const float* __restrict__ Whh1,
                    const float* __restrict__ bih1,
                    const float* __restrict__ bhh1,
                    const float* __restrict__ Wh1,
                    const float* __restrict__ bh1,
                    const float* __restrict__ Wh2,
                    const float* __restrict__ bh2,
                    const float* __restrict__ Cg,
                    float* __restrict__ out) {
    __shared__ __align__(16) float smem[6400 + 3600 + 64 + 64 + 32];
    float* CT  = smem;                  // [f][32][4] padded folded xg0 weights
    float* xs  = smem + 6400;           // [f][CHUNK] transposed x chunk
    float* heL = smem + 10000;          // 64: h_embed
    float* bbL = heL + 64;              // 64: b_in + h_embed
    float* h1L = bbL + 64;              // 32: h1 exchange + final h1 for head

    const int bid = blockIdx.x;
    const int b   = bid >> 2;
    const int e   = bid & 3;
    const int tid = threadIdx.x;
    const int j   = tid & 31;
    const int hlf = tid >> 5;
    const int k0h = hlf << 4;

    // ---- stage h_embed / (b_in + h_embed) (wave-synchronous) ----
    {
        int hor = horizon[b];
        float he = emb[(size_t)hor * ND + tid];
        heL[tid] = he;
        bbL[tid] = he + b_in[tid];
    }

    // ---- gating (every thread computes identically) ----
    float lg[NE];
    #pragma unroll
    for (int q = 0; q < NE; q++) {
        float s = b_gate[q];
        for (int d = 0; d < ND; d++) s += heL[d] * W_gate[q * ND + d];
        lg[q] = s;
    }
    int i1 = 0;
    #pragma unroll
    for (int q = 1; q < NE; q++) if (lg[q] > lg[i1]) i1 = q;
    int i2 = (i1 == 0) ? 1 : 0;
    #pragma unroll
    for (int q = 0; q < NE; q++) if (q != i1 && lg[q] > lg[i2]) i2 = q;
    if (e != i1 && e != i2) return;          // block-uniform
    const float ex2 = expf(lg[i2] - lg[i1]);
    const float wgt = (e == i1) ? (1.f / (1.f + ex2)) : (ex2 / (1.f + ex2));

    // ---- stage folded xg0 weights into LDS, repacking [f][96]->[f][j][4] ----
    {
        const float4* src = (const float4*)(Cg + (size_t)e * NF * G3);
        for (int i4 = tid; i4 < (NF * G3) / 4; i4 += 64) {
            float4 v = src[i4];
            int base = i4 << 2;          // f*96 + g, g0 % 4 == 0
            int f  = base / 96;
            int g0 = base - f * 96;
            int c  = g0 >> 5;            // 0,1,2 (never crosses inside a float4)
            int j0 = g0 & 31;
            float* dst = CT + (((f << 5) + j0) << 2) + c;
            dst[0]  = v.x;
            dst[4]  = v.y;
            dst[8]  = v.z;
            dst[12] = v.w;
        }
    }

    // ---- per-lane weights ----
    // selA: half0 -> Whh0 rows {j, j+32, j+64}; half1 -> Wih1 rows (full 32-k)
    v2f sA0[16], sA1[16], sA2[16];
    // wB: Whh1 rows {j, j+32, j+64}, k-half [k0h, k0h+16)
    v2f wB0[8], wB1[8], wB2[8];
    {
        const float* baseA = (hlf ? Wih1 : Whh0) + (size_t)e * G3 * NH;
        const float* rA0 = baseA + (size_t)j * NH;
        const float* rA1 = baseA + (size_t)(j + 32) * NH;
        const float* rA2 = baseA + (size_t)(j + 64) * NH;
        #pragma unroll
        for (int q4 = 0; q4 < 8; q4++) {
            float4 qa = ((const float4*)rA0)[q4];
            sA0[2*q4] = mkv2(qa.x, qa.y); sA0[2*q4+1] = mkv2(qa.z, qa.w);
            float4 qb = ((const float4*)rA1)[q4];
            sA1[2*q4] = mkv2(qb.x, qb.y); sA1[2*q4+1] = mkv2(qb.z, qb.w);
            float4 qc = ((const float4*)rA2)[q4];
            sA2[2*q4] = mkv2(qc.x, qc.y); sA2[2*q4+1] = mkv2(qc.z, qc.w);
        }
        const float* baseB = Whh1 + (size_t)e * G3 * NH;
        const float* rB0 = baseB + (size_t)j * NH + k0h;
        const float* rB1 = baseB + (size_t)(j + 32) * NH + k0h;
        const float* rB2 = baseB + (size_t)(j + 64) * NH + k0h;
        #pragma unroll
        for (int q4 = 0; q4 < 4; q4++) {
            float4 qa = ((const float4*)rB0)[q4];
            wB0[2*q4] = mkv2(qa.x, qa.y); wB0[2*q4+1] = mkv2(qa.z, qa.w);
            float4 qb = ((const float4*)rB1)[q4];
            wB1[2*q4] = mkv2(qb.x, qb.y); wB1[2*q4+1] = mkv2(qb.z, qb.w);
            float4 qc = ((const float4*)rB2)[q4];
            wB2[2*q4] = mkv2(qc.x, qc.y); wB2[2*q4+1] = mkv2(qc.z, qc.w);
        }
    }
    const float selb0 = hlf ? bih1[e*G3 + j]      : bhh0[e*G3 + j];
    const float selb1 = hlf ? bih1[e*G3 + j + 32] : bhh0[e*G3 + j + 32];
    const float selb2 = hlf ? bih1[e*G3 + j + 64] : bhh0[e*G3 + j + 64];
    const float whb0  = hlf ? 0.f : bhh1[e*G3 + j];
    const float whb1  = hlf ? 0.f : bhh1[e*G3 + j + 32];
    const float whb2  = hlf ? 0.f : bhh1[e*G3 + j + 64];

    // dreg = bih0 + Wih0 @ (b_in + h_embed), added once (half0 side of reduce)
    float dreg0, dreg1, dreg2;
    {
        float s0 = bih0[e*G3 + j], s1 = bih0[e*G3 + j + 32], s2 = bih0[e*G3 + j + 64];
        const float* w0 = Wih0 + ((size_t)e * G3 + j) * ND;
        const float* w1 = Wih0 + ((size_t)e * G3 + j + 32) * ND;
        const float* w2 = Wih0 + ((size_t)e * G3 + j + 64) * ND;
        for (int d = 0; d < ND; d++) {
            float bb = bbL[d];
            s0 += w0[d] * bb; s1 += w1[d] * bb; s2 += w2[d] * bb;
        }
        dreg0 = hlf ? 0.f : s0;
        dreg1 = hlf ? 0.f : s1;
        dreg2 = hlf ? 0.f : s2;
    }

    // ---- pipeline state ----
    v2f h0v[16], h1v[8];
    #pragma unroll
    for (int k = 0; k < 16; k++) h0v[k] = splat2(0.f);
    #pragma unroll
    for (int k = 0; k < 8; k++)  h1v[k] = splat2(0.f);
    float hold = 0.f;                    // half0: h0_j ; half1: h1_j (skewed)
    float lmul = hlf ? 0.f : 1.f;        // neutralizes the fake first L1 step
    if (tid < 32) h1L[tid] = 0.f;

    const float* xg = x + (size_t)b * LSEQ * NF;

    for (int ch = 0; ch < NCHUNK; ch++) {
        // stage x chunk (contiguous float4 global loads), transpose to [f][t]
        {
            const float4* xc4 = (const float4*)(xg + (size_t)ch * CHUNK * NF);
            for (int i4 = tid; i4 < (CHUNK * NF) / 4; i4 += 64) {
                float4 v = xc4[i4];
                int idx = i4 * 4;
                #pragma unroll
                for (int u = 0; u < 4; u++) {
                    int id = idx + u;
                    int it = (int)(((unsigned)id * 5243u) >> 18);   // id/50
                    int f  = id - it * 50;
                    float val = (u == 0) ? v.x : (u == 1) ? v.y : (u == 2) ? v.z : v.w;
                    xs[f * CHUNK + it] = val;
                }
            }
        }

        for (int blk = 0; blk < NBLK; blk++) {
            const int ib0 = blk * TBLK;
            // ---- xg0 partials for TBLK steps (f-split across halves) ----
            v2f a0[4], a1[4], a2[4];
            #pragma unroll
            for (int p = 0; p < 4; p++) {
                a0[p] = splat2(dreg0); a1[p] = splat2(dreg1); a2[p] = splat2(dreg2);
            }
            {
                const int fb = 25 * hlf;
                #pragma unroll
                for (int f = 0; f < 25; f++) {
                    const int fg = fb + f;
                    float4 cv = *(const float4*)(CT + (((fg << 5) + j) << 2));
                    const float4* xp = (const float4*)(xs + fg * CHUNK + ib0);
                    float4 xa = xp[0], xb = xp[1];
                    v2f xv[4] = { mkv2(xa.x, xa.y), mkv2(xa.z, xa.w),
                                  mkv2(xb.x, xb.y), mkv2(xb.z, xb.w) };
                    v2f w0 = splat2(cv.x), w1 = splat2(cv.y), w2 = splat2(cv.z);
                    #pragma unroll
                    for (int p = 0; p < 4; p++) {
                        a0[p] = v2fma(w0, xv[p], a0[p]);
                        a1[p] = v2fma(w1, xv[p], a1[p]);
                        a2[p] = v2fma(w2, xv[p], a2[p]);
                    }
                }
            }
            // cross-half reduce of xg0 (VALU permlane swaps, off the chain)
            #pragma unroll
            for (int p = 0; p < 4; p++) {
                a0[p].x = xor32sum(a0[p].x); a0[p].y = xor32sum(a0[p].y);
                a1[p].x = xor32sum(a1[p].x); a1[p].y = xor32sum(a1[p].y);
                a2[p].x = xor32sum(a2[p].x); a2[p].y = xor32sum(a2[p].y);
            }

            // ---- TBLK pipelined steps: L0(t) on half0 || L1(t-1) on half1 ----
            #pragma unroll
            for (int i = 0; i < TBLK; i++) {
                // B-dots (k-half over h1 from LDS), xor-32 reduce via permlane
                v2f dB0 = mkv2(whb0, 0.f), dB1 = mkv2(whb1, 0.f), dB2 = mkv2(whb2, 0.f);
                #pragma unroll
                for (int k = 0; k < 8; k++) {
                    dB0 = v2fma(wB0[k], h1v[k], dB0);
                    dB1 = v2fma(wB1[k], h1v[k], dB1);
                    dB2 = v2fma(wB2[k], h1v[k], dB2);
                }
                float R0 = xor32sum(dB0.x + dB0.y);
                float R1 = xor32sum(dB1.x + dB1.y);
                float R2 = xor32sum(dB2.x + dB2.y);
                // A-dots: full dots over transported h0
                v2f dA0 = mkv2(selb0, 0.f), dA1 = mkv2(selb1, 0.f), dA2 = mkv2(selb2, 0.f);
                #pragma unroll
                for (int k = 0; k < 16; k++) {
                    dA0 = v2fma(sA0[k], h0v[k], dA0);
                    dA1 = v2fma(sA1[k], h0v[k], dA1);
                    dA2 = v2fma(sA2[k], h0v[k], dA2);
                }
                float A0 = dA0.x + dA0.y, A1 = dA1.x + dA1.y, A2 = dA2.x + dA2.y;
                const float ac0 = a0[i >> 1][i & 1];
                const float ac1 = a1[i >> 1][i & 1];
                const float ac2 = a2[i >> 1][i & 1];
                // gate assembly (uniform instructions, per-half operand select)
                float o0   = hlf ? R0 : ac0;
                float o1   = hlf ? R1 : ac1;
                float npre = hlf ? A2 : ac2;
                float gn   = hlf ? R2 : A2;
                float r = fsig(A0 + o0);
                float z = fsig(A1 + o1);
                float n = ftanh(npre + r * gn);
                float hnew = (n + z * (hold - n)) * lmul;
                hold = hnew;
                lmul = 1.f;
                // h1 exchange via LDS (round trip covered by transport + A-dots)
                if (hlf) h1L[j] = hnew;
                const float4* h1q = (const float4*)(h1L + k0h);
                float4 q0 = h1q[0], q1 = h1q[1], q2 = h1q[2], q3 = h1q[3];
                h1v[0] = mkv2(q0.x, q0.y); h1v[1] = mkv2(q0.z, q0.w);
                h1v[2] = mkv2(q1.x, q1.y); h1v[3] = mkv2(q1.z, q1.w);
                h1v[4] = mkv2(q2.x, q2.y); h1v[5] = mkv2(q2.z, q2.w);
                h1v[6] = mkv2(q3.x, q3.y); h1v[7] = mkv2(q3.z, q3.w);
                // h0 broadcast via v_readlane: VALU-only, no DS latency
                {
                    int hni = __float_as_int(hnew);
                    #pragma unroll
                    for (int k = 0; k < 16; k++) {
                        float e0 = __int_as_float(__builtin_amdgcn_readlane(hni, 2*k));
                        float e1 = __int_as_float(__builtin_amdgcn_readlane(hni, 2*k+1));
                        h0v[k] = mkv2(e0, e1);
                    }
                }
            }
        }
    }

    // ---- epilogue: L1(LSEQ-1) (results used from half1 only) ----
    {
        v2f dA0 = mkv2(selb0, 0.f), dA1 = mkv2(selb1, 0.f), dA2 = mkv2(selb2, 0.f);
        #pragma unroll
        for (int k = 0; k < 16; k++) {
            dA0 = v2fma(sA0[k], h0v[k], dA0);
            dA1 = v2fma(sA1[k], h0v[k], dA1);
            dA2 = v2fma(sA2[k], h0v[k], dA2);
        }
        v2f dB0 = mkv2(whb0, 0.f), dB1 = mkv2(whb1, 0.f), dB2 = mkv2(whb2, 0.f);
        #pragma unroll
        for (int k = 0; k < 8; k++) {
            dB0 = v2fma(wB0[k], h1v[k], dB0);
            dB1 = v2fma(wB1[k], h1v[k], dB1);
            dB2 = v2fma(wB2[k], h1v[k], dB2);
        }
        float A0 = dA0.x + dA0.y, A1 = dA1.x + dA1.y, A2 = dA2.x + dA2.y;
        float R0 = xor32sum(dB0.x + dB0.y);
        float R1 = xor32sum(dB1.x + dB1.y);
        float R2 = xor32sum(dB2.x + dB2.y);
        float r = fsig(A0 + R0);
        float z = fsig(A1 + R1);
        float n = ftanh(A2 + r * R2);
        float hfin = n + z * (hold - n);
        if (hlf) h1L[j] = hfin;
    }

    // ---- head MLP + weighted accumulation ----
    if (tid < 32) {
        float s = bh1[e * NHU + tid];
        const float* wr = Wh1 + ((size_t)e * NHU + tid) * NH;
        #pragma unroll
        for (int d = 0; d < NH; d++) s += wr[d] * h1L[d];
        float hid = fmaxf(s, 0.f);
        float c = hid * Wh2[e * NHU + tid];
        #pragma unroll
        for (int off = 16; off > 0; off >>= 1) c += __shfl_down(c, off, 64);
        if (tid == 0) atomicAdd(out + b, wgt * (c + bh2[e]));
    }
}

extern "C" void kernel_launch(void* const* d_in, const int* in_sizes, int n_in,
                              void* d_out, int out_size, void* d_ws, size_t ws_size,
                              hipStream_t stream) {
    const float* x       = (const float*)d_in[0];
    const int*   horizon = (const int*)  d_in[1];
    const float* W_in    = (const float*)d_in[2];
    const float* b_in    = (const float*)d_in[3];
    const float* emb     = (const float*)d_in[4];
    const float* W_gate  = (const float*)d_in[5];
    const float* b_gate  = (const float*)d_in[6];
    const float* Wih0    = (const float*)d_in[7];
    const float* Whh0    = (const float*)d_in[8];
    const float* bih0    = (const float*)d_in[9];
    const float* bhh0    = (const float*)d_in[10];
    const float* Wih1    = (const float*)d_in[11];
    const float* Whh1    = (const float*)d_in[12];
    const float* bih1    = (const float*)d_in[13];
    const float* bhh1    = (const float*)d_in[14];
    const float* Wh1     = (const float*)d_in[15];
    const float* bh1     = (const float*)d_in[16];
    const float* Wh2     = (const float*)d_in[17];
    const float* bh2     = (const float*)d_in[18];
    float* out = (float*)d_out;
    float* Cg  = (float*)d_ws;   // NE*NF*G3 floats = 76.8 KB

    hipMemsetAsync(d_out, 0, NB * sizeof(float), stream);
    compute_C_kernel<<<dim3(NE), dim3(256), 0, stream>>>(Wih0, W_in, Cg);
    moe_gru_kernel<<<dim3(NB * NE), dim3(64), 0, stream>>>(
        x, horizon, emb, W_gate, b_gate, b_in,
        Wih0, Whh0, bih0, bhh0, Wih1, Whh1, bih1, bhh1,
        Wh1, bh1, Wh2, bh2, Cg, out);
}